// Round 1
// baseline (576.699 us; speedup 1.0000x reference)
//
#include <hip/hip_runtime.h>
#include <stdint.h>

#define SEQ 41
#define KG 8
#define MM 5
#define SITE 20

typedef float f32x4 __attribute__((ext_vector_type(4)));
typedef short bf16x8 __attribute__((ext_vector_type(8)));

__device__ __forceinline__ unsigned short f2bf(float f) {
    union { float f; uint32_t u; } v; v.f = f;
    uint32_t u = v.u;
    u += 0x7fffu + ((u >> 16) & 1u);   // round-to-nearest-even
    return (unsigned short)(u >> 16);
}

// ---------------- Kernel 1: subgraph selection (one thread per batch) -------
__global__ void k_select(const float* __restrict__ att, const float* __restrict__ deg,
                         float* __restrict__ out_idx, int B) {
    int b = blockIdx.x * blockDim.x + threadIdx.x;
    if (b >= B) return;
    const float* d = deg + (size_t)b * SEQ;
    const float* abase = att + (size_t)b * SEQ * SEQ;
    float* outp = out_idx + (size_t)b * (KG * MM);
    uint64_t usedD = 0;
    uint64_t sel = 1ull << SITE;
    for (int g = 0; g < KG; ++g) {
        // argmax over degree excluding already-chosen (top_k order, ties -> lower idx)
        float best = -1e30f; int bi = 0;
        for (int j = 0; j < SEQ; ++j) {
            if (!((usedD >> j) & 1ull)) {
                float v = d[j];
                if (v > best) { best = v; bi = j; }
            }
        }
        usedD |= 1ull << bi;
        const float* row = abase + (size_t)bi * SEQ;
        uint64_t grp = 0;
        for (int m = 0; m < MM; ++m) {
            float pb = -1e30f; int pi = 0;
            for (int j = 0; j < SEQ; ++j) {
                if (!((sel >> j) & 1ull)) {
                    float v = row[j];
                    if (v > pb) { pb = v; pi = j; }
                }
            }
            sel |= 1ull << pi;
            grp |= 1ull << pi;
        }
        // emit set bits in ascending order == jnp.sort
        int pos = 0;
        for (int j = 0; j < SEQ; ++j) {
            if ((grp >> j) & 1ull) { outp[g * MM + pos] = (float)j; ++pos; }
        }
    }
}

// ---------------- Kernel 2: conv1d + double tanh via bf16 MFMA --------------
// out[b,o,h] = tanh(tanh( b1[o] + sum_{k=0..2} sum_{i} x[b,h+k-1,i] * w1d[o,i,k] ))
// Per wave (one batch): Out(48x48) = sum_k Wk(48x64) x Bk(64x48), K padded to 64.
// LDS xbT[c][i] = x[c-1][i] (c=h+k), XOR-swizzled on 16B granules.
__global__ __launch_bounds__(256) void k_conv1d(const float* __restrict__ x,
                                                const float* __restrict__ w1d,
                                                const float* __restrict__ b1d,
                                                float* __restrict__ out_site,
                                                float* __restrict__ out_asite, int B) {
    __shared__ unsigned short lds[4][52 * 64];
    const int tid = threadIdx.x;
    const int wid = tid >> 6;
    const int lane = tid & 63;
    const int b = blockIdx.x * 4 + wid;
    unsigned short* xb = lds[wid];

    const int arow = lane & 15;  // row within 16-tile
    const int kgrp = lane >> 4;  // 0..3

    // Load A fragments (weights) once: afr[k][ks][mt]; A[m=o][K=i] = w1d[(o*41+i)*3+k]
    bf16x8 afr[3][2][3];
#pragma unroll
    for (int k = 0; k < 3; ++k)
#pragma unroll
        for (int ks = 0; ks < 2; ++ks)
#pragma unroll
            for (int mt = 0; mt < 3; ++mt) {
                int o = mt * 16 + arow;
                bf16x8 f;
#pragma unroll
                for (int j = 0; j < 8; ++j) {
                    int i = ks * 32 + kgrp * 8 + j;
                    float v = (o < SEQ && i < SEQ) ? w1d[(o * SEQ + i) * 3 + k] : 0.0f;
                    f[j] = (short)f2bf(v);
                }
                afr[k][ks][mt] = f;
            }

    // zero this wave's LDS region (52*64 halfwords = 832 u64)
    {
        uint64_t* p = (uint64_t*)xb;
#pragma unroll
        for (int it = 0; it < 13; ++it) p[lane + it * 64] = 0ull;
    }
    __syncthreads();

    // stage x transposed+shifted into LDS (bf16, swizzled); emit Asite on the fly
    const float* xp = x + (size_t)b * SEQ * SEQ;
    float* asite = out_asite + (size_t)b * SEQ;
    for (int t = lane; t < SEQ * SEQ; t += 64) {
        int r = t / SEQ, c = t % SEQ;  // x row r, col i=c
        float v = xp[t];
        int cc = r + 1;  // xbT row = (x row)+1
        int hw = cc * 64 + ((((c >> 3) ^ (cc & 7)) & 7) << 3) + (c & 7);
        xb[hw] = f2bf(v);
        if (r == SITE) asite[c] = v;
    }
    __syncthreads();

    f32x4 acc[3][3];
#pragma unroll
    for (int a = 0; a < 3; ++a)
#pragma unroll
        for (int n = 0; n < 3; ++n)
#pragma unroll
            for (int j = 0; j < 4; ++j) acc[a][n][j] = 0.0f;

#pragma unroll
    for (int k = 0; k < 3; ++k) {
#pragma unroll
        for (int ks = 0; ks < 2; ++ks) {
#pragma unroll
            for (int nt = 0; nt < 3; ++nt) {
                int c = nt * 16 + (lane & 15) + k;          // xbT row (h+k)
                int gb = ((ks * 4 + kgrp) ^ (c & 7)) & 7;   // swizzled granule
                const bf16x8 bfrag = *(const bf16x8*)&xb[c * 64 + (gb << 3)];
#pragma unroll
                for (int mt = 0; mt < 3; ++mt)
                    acc[mt][nt] = __builtin_amdgcn_mfma_f32_16x16x32_bf16(
                        afr[k][ks][mt], bfrag, acc[mt][nt], 0, 0, 0);
            }
        }
    }

    // epilogue: +bias, tanh(tanh()), store. C/D: col=lane&15 (h), row=kgrp*4+j (o)
    float* outb = out_site + (size_t)b * SEQ * SEQ;
#pragma unroll
    for (int mt = 0; mt < 3; ++mt) {
#pragma unroll
        for (int nt = 0; nt < 3; ++nt) {
            int h = nt * 16 + (lane & 15);
#pragma unroll
            for (int j = 0; j < 4; ++j) {
                int o = mt * 16 + kgrp * 4 + j;
                if (o < SEQ && h < SEQ) {
                    float v = acc[mt][nt][j] + b1d[o];
                    outb[o * SEQ + h] = tanhf(tanhf(v));
                }
            }
        }
    }
}

// ---------------- Kernel 3: gather + conv2d (block per batch) ---------------
__global__ __launch_bounds__(256) void k_conv2d(const float* __restrict__ x,
                                                const float* __restrict__ w2,
                                                const float* __restrict__ b2,
                                                const float* __restrict__ idxf,
                                                float* __restrict__ out_bag, int B) {
    const int b = blockIdx.x;
    const int tid = threadIdx.x;
    __shared__ float ctx[KG][MM + 2][SEQ + 3];  // [8][7][44], zero border
    __shared__ int ridx[KG * MM];

    if (tid < KG * MM) ridx[tid] = (int)idxf[(size_t)b * KG * MM + tid];
    float* cz = &ctx[0][0][0];
    for (int t = tid; t < KG * (MM + 2) * (SEQ + 3); t += 256) cz[t] = 0.0f;
    __syncthreads();

    const float* xbp = x + (size_t)b * SEQ * SEQ;
    for (int t = tid; t < KG * MM * SEQ; t += 256) {
        int i = t / (MM * SEQ);
        int rem = t % (MM * SEQ);
        int m = rem / SEQ;
        int w = rem % SEQ;
        ctx[i][m + 1][w + 1] = xbp[ridx[i * MM + m] * SEQ + w];
    }
    __syncthreads();

    if (tid < MM * SEQ) {
        int m = tid / SEQ, w = tid % SEQ;
        float acc[KG];
#pragma unroll
        for (int o = 0; o < KG; ++o) acc[o] = b2[o];
#pragma unroll
        for (int i = 0; i < KG; ++i)
#pragma unroll
            for (int kh = 0; kh < 3; ++kh)
#pragma unroll
                for (int kw = 0; kw < 3; ++kw) {
                    float cv = ctx[i][m + kh][w + kw];
#pragma unroll
                    for (int o = 0; o < KG; ++o)
                        acc[o] += cv * w2[((o * KG + i) * 3 + kh) * 3 + kw];
                }
        size_t base = (size_t)b * KG * MM * SEQ + (size_t)m * SEQ + w;
#pragma unroll
        for (int o = 0; o < KG; ++o)
            out_bag[base + (size_t)o * MM * SEQ] = acc[o];
    }
}

extern "C" void kernel_launch(void* const* d_in, const int* in_sizes, int n_in,
                              void* d_out, int out_size, void* d_ws, size_t ws_size,
                              hipStream_t stream) {
    const float* att = (const float*)d_in[0];
    const float* deg = (const float*)d_in[1];
    const float* x   = (const float*)d_in[2];
    const float* w1d = (const float*)d_in[3];
    const float* b1d = (const float*)d_in[4];
    const float* w2d = (const float*)d_in[5];
    const float* b2d = (const float*)d_in[6];
    const int B = in_sizes[1] / SEQ;  // degree is [B, SEQ]

    float* out = (float*)d_out;
    const size_t s_bag   = (size_t)B * KG * MM * SEQ;  // x_bag  [B,8,5,41]
    const size_t s_asite = (size_t)B * SEQ;            // Asite  [B,1,41]
    const size_t s_site  = (size_t)B * SEQ * SEQ;      // x_site [B,41,41]
    float* o_bag   = out;
    float* o_asite = out + s_bag;
    float* o_site  = out + s_bag + s_asite;
    float* o_idx   = out + s_bag + s_asite + s_site;   // index_all as f32 [B,8,5]

    k_select<<<(B + 63) / 64, 64, 0, stream>>>(att, deg, o_idx, B);
    k_conv1d<<<B / 4, 256, 0, stream>>>(x, w1d, b1d, o_site, o_asite, B);
    k_conv2d<<<B, 256, 0, stream>>>(x, w2d, b2d, o_idx, o_bag, B);
}

// Round 3
// 328.850 us; speedup vs baseline: 1.7537x; 1.7537x over previous
//
#include <hip/hip_runtime.h>
#include <stdint.h>

#define SEQ 41
#define KG 8
#define MM 5
#define SITE 20

typedef float f32x4 __attribute__((ext_vector_type(4)));
typedef short bf16x8 __attribute__((ext_vector_type(8)));

__device__ __forceinline__ unsigned short f2bf(float f) {
    union { float f; uint32_t u; } v; v.f = f;
    uint32_t u = v.u;
    u += 0x7fffu + ((u >> 16) & 1u);   // round-to-nearest-even
    return (unsigned short)(u >> 16);
}

// ---------------- Kernel 1: subgraph selection (one WAVE per batch) ---------
// argmax = 6-step shfl_xor max-reduce, then ballot(v==max) -> lowest lane
// (exact match to top_k tie order: ties -> lower index).
__device__ __forceinline__ int wave_argmax(float v) {
    float m = v;
#pragma unroll
    for (int off = 32; off; off >>= 1) {
        float o = __shfl_xor(m, off);
        m = fmaxf(m, o);
    }
    unsigned long long bal = __ballot(v == m);
    return __ffsll(bal) - 1;
}

__global__ __launch_bounds__(256) void k_select(const float* __restrict__ att,
                                                const float* __restrict__ deg,
                                                float* __restrict__ out_idx, int B) {
    const int wid = threadIdx.x >> 6;
    const int lane = threadIdx.x & 63;
    const int b = blockIdx.x * 4 + wid;
    if (b >= B) return;

    float dv = (lane < SEQ) ? deg[(size_t)b * SEQ + lane] : -1e30f;
    const float* abase = att + (size_t)b * SEQ * SEQ;
    float* outp = out_idx + (size_t)b * (KG * MM);

    bool my_sel = (lane == SITE);  // per-lane "already selected" flag

#pragma unroll
    for (int g = 0; g < KG; ++g) {
        int bi = wave_argmax(dv);
        if (lane == bi) dv = -1e30f;

        float rv = (lane < SEQ) ? abase[(size_t)bi * SEQ + lane] : -1e30f;
        if (my_sel) rv = -1e30f;

        unsigned long long grp = 0;
#pragma unroll
        for (int m = 0; m < MM; ++m) {
            int pi = wave_argmax(rv);
            if (lane == pi) { rv = -1e30f; my_sel = true; }
            grp |= 1ull << pi;
        }
        // emit set bits ascending == jnp.sort; lane t finds t-th set bit
        if (lane < MM) {
            unsigned long long gg = grp;
            for (int t = 0; t < lane; ++t) gg &= gg - 1;
            outp[g * MM + lane] = (float)(__ffsll(gg) - 1);
        }
    }
}

// ---------------- Kernel 2: conv1d + double tanh via bf16 MFMA --------------
// out[b,o,h] = tanh(tanh( b1[o] + sum_{k=0..2} sum_{i} x[b,h+k-1,i] * w1d[o,i,k] ))
// Per wave (one batch): Out(48x48) = sum_k Wk(48x64) x Bk(64x48), K padded to 64.
// LDS xbT[c][i] = x[c-1][i] (c=h+k), XOR-swizzled on 16B granules.
__global__ __launch_bounds__(256) void k_conv1d(const float* __restrict__ x,
                                                const float* __restrict__ w1d,
                                                const float* __restrict__ b1d,
                                                float* __restrict__ out_site,
                                                float* __restrict__ out_asite, int B) {
    __shared__ unsigned short lds[4][52 * 64];
    const int tid = threadIdx.x;
    const int wid = tid >> 6;
    const int lane = tid & 63;
    const int b = blockIdx.x * 4 + wid;
    unsigned short* xb = lds[wid];

    const int arow = lane & 15;  // row within 16-tile
    const int kgrp = lane >> 4;  // 0..3

    // Load A fragments (weights) once: afr[k][ks][mt]; A[m=o][K=i] = w1d[(o*41+i)*3+k]
    bf16x8 afr[3][2][3];
#pragma unroll
    for (int k = 0; k < 3; ++k)
#pragma unroll
        for (int ks = 0; ks < 2; ++ks)
#pragma unroll
            for (int mt = 0; mt < 3; ++mt) {
                int o = mt * 16 + arow;
                bf16x8 f;
#pragma unroll
                for (int j = 0; j < 8; ++j) {
                    int i = ks * 32 + kgrp * 8 + j;
                    float v = (o < SEQ && i < SEQ) ? w1d[(o * SEQ + i) * 3 + k] : 0.0f;
                    f[j] = (short)f2bf(v);
                }
                afr[k][ks][mt] = f;
            }

    // zero this wave's LDS region (52*64 halfwords = 832 u64)
    {
        uint64_t* p = (uint64_t*)xb;
#pragma unroll
        for (int it = 0; it < 13; ++it) p[lane + it * 64] = 0ull;
    }
    __syncthreads();

    // stage x transposed+shifted into LDS (bf16, swizzled); emit Asite on the fly
    const float* xp = x + (size_t)b * SEQ * SEQ;
    float* asite = out_asite + (size_t)b * SEQ;
    for (int t = lane; t < SEQ * SEQ; t += 64) {
        int r = t / SEQ, c = t % SEQ;  // x row r, col i=c
        float v = xp[t];
        int cc = r + 1;  // xbT row = (x row)+1
        int hw = cc * 64 + ((((c >> 3) ^ (cc & 7)) & 7) << 3) + (c & 7);
        xb[hw] = f2bf(v);
        if (r == SITE) asite[c] = v;
    }
    __syncthreads();

    f32x4 acc[3][3];
#pragma unroll
    for (int a = 0; a < 3; ++a)
#pragma unroll
        for (int n = 0; n < 3; ++n)
#pragma unroll
            for (int j = 0; j < 4; ++j) acc[a][n][j] = 0.0f;

#pragma unroll
    for (int k = 0; k < 3; ++k) {
#pragma unroll
        for (int ks = 0; ks < 2; ++ks) {
#pragma unroll
            for (int nt = 0; nt < 3; ++nt) {
                int c = nt * 16 + (lane & 15) + k;          // xbT row (h+k)
                int gb = ((ks * 4 + kgrp) ^ (c & 7)) & 7;   // swizzled granule
                const bf16x8 bfrag = *(const bf16x8*)&xb[c * 64 + (gb << 3)];
#pragma unroll
                for (int mt = 0; mt < 3; ++mt)
                    acc[mt][nt] = __builtin_amdgcn_mfma_f32_16x16x32_bf16(
                        afr[k][ks][mt], bfrag, acc[mt][nt], 0, 0, 0);
            }
        }
    }

    // epilogue: +bias, tanh(tanh()), store. C/D: col=lane&15 (h), row=kgrp*4+j (o)
    float* outb = out_site + (size_t)b * SEQ * SEQ;
#pragma unroll
    for (int mt = 0; mt < 3; ++mt) {
#pragma unroll
        for (int nt = 0; nt < 3; ++nt) {
            int h = nt * 16 + (lane & 15);
#pragma unroll
            for (int j = 0; j < 4; ++j) {
                int o = mt * 16 + kgrp * 4 + j;
                if (o < SEQ && h < SEQ) {
                    float v = acc[mt][nt][j] + b1d[o];
                    outb[o * SEQ + h] = tanhf(tanhf(v));
                }
            }
        }
    }
}

// ---------------- Kernel 3: gather + conv2d (block per batch) ---------------
__global__ __launch_bounds__(256) void k_conv2d(const float* __restrict__ x,
                                                const float* __restrict__ w2,
                                                const float* __restrict__ b2,
                                                const float* __restrict__ idxf,
                                                float* __restrict__ out_bag, int B) {
    const int b = blockIdx.x;
    const int tid = threadIdx.x;
    __shared__ float ctx[KG][MM + 2][SEQ + 3];  // [8][7][44], zero border
    __shared__ int ridx[KG * MM];

    if (tid < KG * MM) ridx[tid] = (int)idxf[(size_t)b * KG * MM + tid];
    float* cz = &ctx[0][0][0];
    for (int t = tid; t < KG * (MM + 2) * (SEQ + 3); t += 256) cz[t] = 0.0f;
    __syncthreads();

    const float* xbp = x + (size_t)b * SEQ * SEQ;
    for (int t = tid; t < KG * MM * SEQ; t += 256) {
        int i = t / (MM * SEQ);
        int rem = t % (MM * SEQ);
        int m = rem / SEQ;
        int w = rem % SEQ;
        ctx[i][m + 1][w + 1] = xbp[ridx[i * MM + m] * SEQ + w];
    }
    __syncthreads();

    if (tid < MM * SEQ) {
        int m = tid / SEQ, w = tid % SEQ;
        float acc[KG];
#pragma unroll
        for (int o = 0; o < KG; ++o) acc[o] = b2[o];
#pragma unroll
        for (int i = 0; i < KG; ++i)
#pragma unroll
            for (int kh = 0; kh < 3; ++kh)
#pragma unroll
                for (int kw = 0; kw < 3; ++kw) {
                    float cv = ctx[i][m + kh][w + kw];
#pragma unroll
                    for (int o = 0; o < KG; ++o)
                        acc[o] += cv * w2[((o * KG + i) * 3 + kh) * 3 + kw];
                }
        size_t base = (size_t)b * KG * MM * SEQ + (size_t)m * SEQ + w;
#pragma unroll
        for (int o = 0; o < KG; ++o)
            out_bag[base + (size_t)o * MM * SEQ] = acc[o];
    }
}

extern "C" void kernel_launch(void* const* d_in, const int* in_sizes, int n_in,
                              void* d_out, int out_size, void* d_ws, size_t ws_size,
                              hipStream_t stream) {
    const float* att = (const float*)d_in[0];
    const float* deg = (const float*)d_in[1];
    const float* x   = (const float*)d_in[2];
    const float* w1d = (const float*)d_in[3];
    const float* b1d = (const float*)d_in[4];
    const float* w2d = (const float*)d_in[5];
    const float* b2d = (const float*)d_in[6];
    const int B = in_sizes[1] / SEQ;  // degree is [B, SEQ]

    float* out = (float*)d_out;
    const size_t s_bag   = (size_t)B * KG * MM * SEQ;  // x_bag  [B,8,5,41]
    const size_t s_asite = (size_t)B * SEQ;            // Asite  [B,1,41]
    const size_t s_site  = (size_t)B * SEQ * SEQ;      // x_site [B,41,41]
    float* o_bag   = out;
    float* o_asite = out + s_bag;
    float* o_site  = out + s_bag + s_asite;
    float* o_idx   = out + s_bag + s_asite + s_site;   // index_all as f32 [B,8,5]

    k_select<<<(B + 3) / 4, 256, 0, stream>>>(att, deg, o_idx, B);
    k_conv1d<<<B / 4, 256, 0, stream>>>(x, w1d, b1d, o_site, o_asite, B);
    k_conv2d<<<B, 256, 0, stream>>>(x, w2d, b2d, o_idx, o_bag, B);
}

// Round 4
// 228.455 us; speedup vs baseline: 2.5243x; 1.4395x over previous
//
#include <hip/hip_runtime.h>
#include <stdint.h>

#define SEQ 41
#define KG 8
#define MM 5
#define SITE 20

typedef float f32x4 __attribute__((ext_vector_type(4)));
typedef short bf16x8 __attribute__((ext_vector_type(8)));

__device__ __forceinline__ unsigned short f2bf(float f) {
    union { float f; uint32_t u; } v; v.f = f;
    uint32_t u = v.u;
    u += 0x7fffu + ((u >> 16) & 1u);   // round-to-nearest-even
    return (unsigned short)(u >> 16);
}

// exact-shape fast tanh: 1 - 2/(e^{2x}+1); correct limits at +/-inf, ~1e-6 err
__device__ __forceinline__ float fast_tanh(float x) {
    float e = __builtin_amdgcn_exp2f(x * 2.8853900817779268f);  // e^{2x}
    return 1.0f - 2.0f * __builtin_amdgcn_rcpf(e + 1.0f);
}

// ---------------- Kernel 0: weight fragment precompute (runs once/call) ----
// Layout: wf_u16[f*512 + lane*8 + j], f=(k*2+ks)*3+mt; A[m=o][K=i]=w1d[(o*41+i)*3+k]
__global__ void k_wprep(const float* __restrict__ w1d, unsigned short* __restrict__ wf) {
    for (int p = threadIdx.x; p < 18 * 64; p += 256) {
        int f = p >> 6, lane = p & 63;
        int k = f / 6, ks = (f / 3) % 2, mt = f % 3;
        int o = mt * 16 + (lane & 15);
#pragma unroll
        for (int j = 0; j < 8; ++j) {
            int i = ks * 32 + (lane >> 4) * 8 + j;
            float v = (o < SEQ && i < SEQ) ? w1d[(o * SEQ + i) * 3 + k] : 0.0f;
            wf[(size_t)p * 8 + j] = f2bf(v);
        }
    }
}

// ---------------- Kernel 1: subgraph selection (one WAVE per batch) ---------
__device__ __forceinline__ int wave_argmax(float v) {
    float m = v;
#pragma unroll
    for (int off = 32; off; off >>= 1) {
        float o = __shfl_xor(m, off);
        m = fmaxf(m, o);
    }
    unsigned long long bal = __ballot(v == m);
    return __ffsll((unsigned long long)bal) - 1;
}

__global__ __launch_bounds__(256) void k_select(const float* __restrict__ att,
                                                const float* __restrict__ deg,
                                                float* __restrict__ out_idx, int B) {
    const int wid = threadIdx.x >> 6;
    const int lane = threadIdx.x & 63;
    const int b = blockIdx.x * 4 + wid;
    if (b >= B) return;

    float dv = (lane < SEQ) ? deg[(size_t)b * SEQ + lane] : -1e30f;
    const float* abase = att + (size_t)b * SEQ * SEQ;
    float* outp = out_idx + (size_t)b * (KG * MM);

    bool my_sel = (lane == SITE);

#pragma unroll
    for (int g = 0; g < KG; ++g) {
        int bi = wave_argmax(dv);
        if (lane == bi) dv = -1e30f;

        float rv = (lane < SEQ) ? abase[(size_t)bi * SEQ + lane] : -1e30f;
        if (my_sel) rv = -1e30f;

        unsigned long long grp = 0;
#pragma unroll
        for (int m = 0; m < MM; ++m) {
            int pi = wave_argmax(rv);
            if (lane == pi) { rv = -1e30f; my_sel = true; }
            grp |= 1ull << pi;
        }
        if (lane < MM) {
            unsigned long long gg = grp;
            for (int t = 0; t < lane; ++t) gg &= gg - 1;
            outp[g * MM + lane] = (float)(__ffsll((unsigned long long)gg) - 1);
        }
    }
}

// ---------------- Kernel 2: conv1d + double tanh via bf16 MFMA --------------
// Per wave (one batch), wave-private LDS, NO block barriers.
// LDS rows: row c holds x[c-1][0..40] bf16, stride 72 hw (144 B) -> 2-way-free banks.
// Rows 0 and 42 zero (shift padding); cols 41..63 zero (K padding, A-side also 0).
#define ROWS 50
#define RST 72
__global__ __launch_bounds__(256) void k_conv1d(const float* __restrict__ x,
                                                const bf16x8* __restrict__ wf,
                                                const float* __restrict__ b1d,
                                                float* __restrict__ out_site,
                                                float* __restrict__ out_asite, int B) {
    __shared__ unsigned short lds[4][ROWS * RST];
    const int tid = threadIdx.x;
    const int wid = tid >> 6;
    const int lane = tid & 63;
    const int b = blockIdx.x * 4 + wid;
    unsigned short* xb = lds[wid];

    // A fragments: 18 coalesced 16B loads from precomputed d_ws (L2-hot)
    bf16x8 afr[18];
#pragma unroll
    for (int f = 0; f < 18; ++f) afr[f] = wf[f * 64 + lane];

    // zero the whole wave-private region (NaN-safe K/shift padding)
    {
        f32x4* z = (f32x4*)xb;
        const f32x4 zv = {0.f, 0.f, 0.f, 0.f};
#pragma unroll
        for (int it = 0; it < 8; ++it) {
            int idx = lane + it * 64;
            if (idx < ROWS * RST / 8) z[idx] = zv;
        }
    }

    // stage x rows -> lds rows 1..41, bf16 by truncation (high half write)
    const float* xp = x + (size_t)b * (SEQ * SEQ);
    if (lane < SEQ) {
#pragma unroll
        for (int r = 0; r < SEQ; ++r) {
            union { float f; unsigned short s[2]; } u;
            u.f = xp[r * SEQ + lane];
            xb[(r + 1) * RST + lane] = u.s[1];
        }
        out_asite[(size_t)b * SEQ + lane] = xp[SITE * SEQ + lane];
    }
    asm volatile("s_waitcnt lgkmcnt(0)" ::: "memory");

    const int h16 = lane & 15;
    const int kgrp = lane >> 4;

    f32x4 acc[3][3];
#pragma unroll
    for (int a = 0; a < 3; ++a)
#pragma unroll
        for (int n = 0; n < 3; ++n)
#pragma unroll
            for (int j = 0; j < 4; ++j) acc[a][n][j] = 0.0f;

#pragma unroll
    for (int k = 0; k < 3; ++k) {
#pragma unroll
        for (int ks = 0; ks < 2; ++ks) {
#pragma unroll
            for (int nt = 0; nt < 3; ++nt) {
                int c = nt * 16 + h16 + k;
                const bf16x8 bfrag = *(const bf16x8*)&xb[c * RST + (ks * 4 + kgrp) * 8];
#pragma unroll
                for (int mt = 0; mt < 3; ++mt)
                    acc[mt][nt] = __builtin_amdgcn_mfma_f32_16x16x32_bf16(
                        afr[(k * 2 + ks) * 3 + mt], bfrag, acc[mt][nt], 0, 0, 0);
            }
        }
    }

    // epilogue: +bias, double fast-tanh, predicated store
    float* outb = out_site + (size_t)b * (SEQ * SEQ);
#pragma unroll
    for (int mt = 0; mt < 3; ++mt) {
#pragma unroll
        for (int nt = 0; nt < 3; ++nt) {
            int h = nt * 16 + h16;
#pragma unroll
            for (int j = 0; j < 4; ++j) {
                int o = mt * 16 + kgrp * 4 + j;
                if (o < SEQ && h < SEQ) {
                    float v = acc[mt][nt][j] + b1d[o];
                    outb[o * SEQ + h] = fast_tanh(fast_tanh(v));
                }
            }
        }
    }
}

// ---------------- Kernel 3: gather + conv2d (block per batch) ---------------
__global__ __launch_bounds__(256) void k_conv2d(const float* __restrict__ x,
                                                const float* __restrict__ w2,
                                                const float* __restrict__ b2,
                                                const float* __restrict__ idxf,
                                                float* __restrict__ out_bag, int B) {
    const int b = blockIdx.x;
    const int tid = threadIdx.x;
    __shared__ float ctx[KG][MM + 2][SEQ + 3];  // [8][7][44], zero border
    __shared__ int ridx[KG * MM];

    if (tid < KG * MM) ridx[tid] = (int)idxf[(size_t)b * KG * MM + tid];
    float* cz = &ctx[0][0][0];
    for (int t = tid; t < KG * (MM + 2) * (SEQ + 3); t += 256) cz[t] = 0.0f;
    __syncthreads();

    const float* xbp = x + (size_t)b * SEQ * SEQ;
    for (int t = tid; t < KG * MM * SEQ; t += 256) {
        int i = t / (MM * SEQ);
        int rem = t % (MM * SEQ);
        int m = rem / SEQ;
        int w = rem % SEQ;
        ctx[i][m + 1][w + 1] = xbp[ridx[i * MM + m] * SEQ + w];
    }
    __syncthreads();

    if (tid < MM * SEQ) {
        int m = tid / SEQ, w = tid % SEQ;
        float acc[KG];
#pragma unroll
        for (int o = 0; o < KG; ++o) acc[o] = b2[o];
#pragma unroll
        for (int i = 0; i < KG; ++i)
#pragma unroll
            for (int kh = 0; kh < 3; ++kh)
#pragma unroll
                for (int kw = 0; kw < 3; ++kw) {
                    float cv = ctx[i][m + kh][w + kw];
#pragma unroll
                    for (int o = 0; o < KG; ++o)
                        acc[o] += cv * w2[((o * KG + i) * 3 + kh) * 3 + kw];
                }
        size_t base = (size_t)b * KG * MM * SEQ + (size_t)m * SEQ + w;
#pragma unroll
        for (int o = 0; o < KG; ++o)
            out_bag[base + (size_t)o * MM * SEQ] = acc[o];
    }
}

extern "C" void kernel_launch(void* const* d_in, const int* in_sizes, int n_in,
                              void* d_out, int out_size, void* d_ws, size_t ws_size,
                              hipStream_t stream) {
    const float* att = (const float*)d_in[0];
    const float* deg = (const float*)d_in[1];
    const float* x   = (const float*)d_in[2];
    const float* w1d = (const float*)d_in[3];
    const float* b1d = (const float*)d_in[4];
    const float* w2d = (const float*)d_in[5];
    const float* b2d = (const float*)d_in[6];
    const int B = in_sizes[1] / SEQ;  // degree is [B, SEQ]

    float* out = (float*)d_out;
    const size_t s_bag   = (size_t)B * KG * MM * SEQ;  // x_bag  [B,8,5,41]
    const size_t s_asite = (size_t)B * SEQ;            // Asite  [B,1,41]
    const size_t s_site  = (size_t)B * SEQ * SEQ;      // x_site [B,41,41]
    float* o_bag   = out;
    float* o_asite = out + s_bag;
    float* o_site  = out + s_bag + s_asite;
    float* o_idx   = out + s_bag + s_asite + s_site;   // index_all as f32 [B,8,5]

    k_wprep<<<1, 256, 0, stream>>>(w1d, (unsigned short*)d_ws);
    k_select<<<(B + 3) / 4, 256, 0, stream>>>(att, deg, o_idx, B);
    k_conv1d<<<B / 4, 256, 0, stream>>>(x, (const bf16x8*)d_ws, b1d, o_site, o_asite, B);
    k_conv2d<<<B, 256, 0, stream>>>(x, w2d, b2d, o_idx, o_bag, B);
}